// Round 1
// baseline (4082.916 us; speedup 1.0000x reference)
//
#include <hip/hip_runtime.h>
#include <cstdint>
#include <cstddef>

#define N_E 2048
#define N_I 512
#define N_TOT 2560
#define BATCH 64
#define TSTEPS 512
#define INDIM 128
#define CAP (1u << 20)   // nz capacity (expected ~330K, mask@10% then relu -> ~5%)

// ------------------------------------------------------------------
// CSC build: counts -> scan -> fill.  Combined pre-neuron index:
//   col 0..2047   : E presynaptic j   (targets: Wee col j -> post 0..2047 (+),
//                                               Wie col j -> post 2048+r (+))
//   col 2048..2559: I presynaptic j   (targets: Wei col j -> post 0..2047 (-),
//                                               Wii col j -> post 2048+r (-))
// ------------------------------------------------------------------
__global__ void count_kernel(const float* __restrict__ Wee, const float* __restrict__ Wie,
                             const float* __restrict__ Wei, const float* __restrict__ Wii,
                             unsigned* __restrict__ cnt)
{
    const long EE = (long)N_E * N_E;      // 4194304
    const long IE = (long)N_I * N_E;      // 1048576
    const long EI = (long)N_E * N_I;      // 1048576
    const long II = (long)N_I * N_I;      // 262144
    long idx = (long)blockIdx.x * 256 + threadIdx.x;
    long total = EE + IE + EI + II;
    if (idx >= total) return;
    float v; int col;
    if (idx < EE) {
        v = Wee[idx]; col = (int)(idx & (N_E - 1));
    } else if (idx < EE + IE) {
        long j = idx - EE; v = Wie[j]; col = (int)(j & (N_E - 1));
    } else if (idx < EE + IE + EI) {
        long j = idx - EE - IE; v = Wei[j]; col = N_E + (int)(j & (N_I - 1));
    } else {
        long j = idx - EE - IE - EI; v = Wii[j]; col = N_E + (int)(j & (N_I - 1));
    }
    if (v > 0.0f) atomicAdd(&cnt[col], 1u);
}

__global__ void scan_kernel(const unsigned* __restrict__ cnt,
                            unsigned* __restrict__ colptr, unsigned* __restrict__ cursor)
{
    __shared__ unsigned sums[256];
    int t = threadIdx.x;
    int base = t * 10;                 // 2560 = 256 * 10
    unsigned loc[10];
    unsigned s = 0;
    for (int i = 0; i < 10; ++i) { loc[i] = s; s += cnt[base + i]; }
    sums[t] = s;
    __syncthreads();
    if (t == 0) {
        unsigned a = 0;
        for (int i = 0; i < 256; ++i) { unsigned v = sums[i]; sums[i] = a; a += v; }
    }
    __syncthreads();
    unsigned offt = sums[t];
    for (int i = 0; i < 10; ++i) {
        unsigned v = offt + loc[i];
        if (v > CAP) v = CAP;
        colptr[base + i] = v;
        cursor[base + i] = v;
    }
    if (t == 255) {
        unsigned tot = offt + s;
        if (tot > CAP) tot = CAP;
        colptr[N_TOT] = tot;
    }
}

__global__ void fill_kernel(const float* __restrict__ Wee, const float* __restrict__ Wie,
                            const float* __restrict__ Wei, const float* __restrict__ Wii,
                            unsigned* __restrict__ cursor,
                            unsigned* __restrict__ nzp, float* __restrict__ nzv)
{
    const long EE = (long)N_E * N_E;
    const long IE = (long)N_I * N_E;
    const long EI = (long)N_E * N_I;
    const long II = (long)N_I * N_I;
    long idx = (long)blockIdx.x * 256 + threadIdx.x;
    long total = EE + IE + EI + II;
    if (idx >= total) return;
    float v; int col; int post; bool neg;
    if (idx < EE) {
        int r = (int)(idx >> 11), c = (int)(idx & (N_E - 1));
        v = Wee[idx]; post = r; col = c; neg = false;
    } else if (idx < EE + IE) {
        long j = idx - EE;
        int r = (int)(j >> 11), c = (int)(j & (N_E - 1));
        v = Wie[j]; post = N_E + r; col = c; neg = false;
    } else if (idx < EE + IE + EI) {
        long j = idx - EE - IE;
        int r = (int)(j >> 9), c = (int)(j & (N_I - 1));
        v = Wei[j]; post = r; col = N_E + c; neg = true;
    } else {
        long j = idx - EE - IE - EI;
        int r = (int)(j >> 9), c = (int)(j & (N_I - 1));
        v = Wii[j]; post = N_E + r; col = N_E + c; neg = true;
    }
    if (v > 0.0f) {
        unsigned pos = atomicAdd(&cursor[col], 1u);
        if (pos < CAP) {
            nzp[pos] = (unsigned)post;
            nzv[pos] = neg ? -v : v;
        }
    }
}

// ------------------------------------------------------------------
// Input projection GEMM: out[(tl*64+b)*2560 + n] = dot(x[b, t0+tl, :], W[n, :])
// M = tc*64 (row m -> tl = m>>6, b = m&63), N = 2560, K = 128.
// BM=128, BN=64, BK=32, 256 threads, 8x4 micro-tile.
// ------------------------------------------------------------------
#define PBM 128
#define PBN 64
#define PBK 32
__global__ __launch_bounds__(256) void proj_kernel(
    const float* __restrict__ x, const float* __restrict__ We, const float* __restrict__ Wi,
    float* __restrict__ out, int t0)
{
    __shared__ __align__(16) float As[PBK][132];  // k-major, padded (132*4=528, 16B mult)
    __shared__ __align__(16) float Bs[PBK][68];   // 68*4=272, 16B mult
    int tid = threadIdx.x;
    int bx = blockIdx.x, by = blockIdx.y;
    int tx = tid & 15, ty = tid >> 4;
    float acc[8][4];
#pragma unroll
    for (int i = 0; i < 8; ++i)
#pragma unroll
        for (int j = 0; j < 4; ++j) acc[i][j] = 0.0f;

    for (int kb = 0; kb < INDIM; kb += PBK) {
        // stage A: 128 rows x 32 k = 1024 float4 / 256 thr = 4 each
#pragma unroll
        for (int it = 0; it < 4; ++it) {
            int idx = it * 256 + tid;
            int kq = idx & 7, ml = idx >> 3;
            int m = by * PBM + ml;
            int b = m & 63, tl = m >> 6;
            const float* arow = x + ((size_t)b * TSTEPS + (size_t)(t0 + tl)) * INDIM;
            float4 v = *(const float4*)(arow + kb + kq * 4);
            As[kq * 4 + 0][ml] = v.x; As[kq * 4 + 1][ml] = v.y;
            As[kq * 4 + 2][ml] = v.z; As[kq * 4 + 3][ml] = v.w;
        }
        // stage B: 64 rows x 32 k = 512 float4 / 256 thr = 2 each
#pragma unroll
        for (int it = 0; it < 2; ++it) {
            int idx = it * 256 + tid;
            int kq = idx & 7, nl = idx >> 3;
            int n = bx * PBN + nl;
            const float* brow = (n < N_E) ? (We + (size_t)n * INDIM)
                                          : (Wi + (size_t)(n - N_E) * INDIM);
            float4 v = *(const float4*)(brow + kb + kq * 4);
            Bs[kq * 4 + 0][nl] = v.x; Bs[kq * 4 + 1][nl] = v.y;
            Bs[kq * 4 + 2][nl] = v.z; Bs[kq * 4 + 3][nl] = v.w;
        }
        __syncthreads();
#pragma unroll
        for (int k = 0; k < PBK; ++k) {
            float4 a0 = *(const float4*)&As[k][ty * 8];
            float4 a1 = *(const float4*)&As[k][ty * 8 + 4];
            float4 b0 = *(const float4*)&Bs[k][tx * 4];
            float a[8] = {a0.x, a0.y, a0.z, a0.w, a1.x, a1.y, a1.z, a1.w};
            float bb[4] = {b0.x, b0.y, b0.z, b0.w};
#pragma unroll
            for (int i = 0; i < 8; ++i)
#pragma unroll
                for (int j = 0; j < 4; ++j)
                    acc[i][j] = fmaf(a[i], bb[j], acc[i][j]);
        }
        __syncthreads();
    }
#pragma unroll
    for (int i = 0; i < 8; ++i) {
        int m = by * PBM + ty * 8 + i;
        float4 o = make_float4(acc[i][0], acc[i][1], acc[i][2], acc[i][3]);
        *(float4*)(out + (size_t)m * N_TOT + bx * PBN + tx * 4) = o;
    }
}

// ------------------------------------------------------------------
// Persistent per-batch LIF sim over tc steps. One block per batch.
// ------------------------------------------------------------------
__global__ __launch_bounds__(1024) void sim_kernel(
    const float* __restrict__ i_inp,   // precomputed input currents; may be null
    const float* __restrict__ x, const float* __restrict__ We_in, const float* __restrict__ Wi_in,
    const unsigned* __restrict__ colptr, const unsigned* __restrict__ nzp, const float* __restrict__ nzv,
    float* __restrict__ gv_e, float* __restrict__ gi_e,
    float* __restrict__ gv_i, float* __restrict__ gi_i,
    unsigned* __restrict__ g_cnt, int* __restrict__ g_list, int* __restrict__ g_nspk,
    int t0, int tc, int first)
{
    __shared__ float v_e[N_E], i_e[N_E];
    __shared__ float v_i[N_I], i_i[N_I];
    __shared__ float I_acc[N_TOT];
    __shared__ unsigned cnt[N_E];
    __shared__ int list_s[N_TOT];
    __shared__ int nspk_s;
    __shared__ float x_s[INDIM];

    int b = blockIdx.x, tid = threadIdx.x;

    if (first) {
        for (int n = tid; n < N_E; n += 1024) { v_e[n] = 0.f; i_e[n] = 0.f; cnt[n] = 0u; }
        for (int n = tid; n < N_I; n += 1024) { v_i[n] = 0.f; i_i[n] = 0.f; }
        if (tid == 0) nspk_s = 0;
        __syncthreads();
    } else {
        for (int n = tid; n < N_E; n += 1024) {
            v_e[n] = gv_e[(size_t)b * N_E + n];
            i_e[n] = gi_e[(size_t)b * N_E + n];
            cnt[n] = g_cnt[(size_t)b * N_E + n];
        }
        for (int n = tid; n < N_I; n += 1024) {
            v_i[n] = gv_i[(size_t)b * N_I + n];
            i_i[n] = gi_i[(size_t)b * N_I + n];
        }
        if (tid == 0) nspk_s = g_nspk[b];
        __syncthreads();
        for (int s = tid; s < nspk_s; s += 1024) list_s[s] = g_list[(size_t)b * N_TOT + s];
        __syncthreads();
    }

    for (int tl = 0; tl < tc; ++tl) {
        // ---- phase 1: input currents into I_acc ----
        if (i_inp) {
            const float* src = i_inp + ((size_t)tl * BATCH + b) * N_TOT;
            for (int n = tid; n < N_TOT; n += 1024) I_acc[n] = src[n];
        } else {
            const float* xr = x + ((size_t)b * TSTEPS + (size_t)(t0 + tl)) * INDIM;
            if (tid < INDIM) x_s[tid] = xr[tid];
            __syncthreads();
            for (int n = tid; n < N_TOT; n += 1024) {
                const float* wr = (n < N_E) ? (We_in + (size_t)n * INDIM)
                                            : (Wi_in + (size_t)(n - N_E) * INDIM);
                float a = 0.f;
#pragma unroll
                for (int k = 0; k < INDIM; k += 4) {
                    float4 w = *(const float4*)(wr + k);
                    a = fmaf(w.x, x_s[k + 0], a);
                    a = fmaf(w.y, x_s[k + 1], a);
                    a = fmaf(w.z, x_s[k + 2], a);
                    a = fmaf(w.w, x_s[k + 3], a);
                }
                I_acc[n] = a;
            }
        }
        __syncthreads();

        // ---- phase 2: spike-driven scatter (prev step's spikes) ----
        {
            int wid = tid >> 6, lane = tid & 63;
            int ns = nspk_s;
            for (int s = wid; s < ns; s += 16) {
                int j = list_s[s];
                unsigned beg = colptr[j], end = colptr[j + 1];
                for (unsigned p = beg + lane; p < end; p += 64)
                    atomicAdd(&I_acc[nzp[p]], nzv[p]);
            }
        }
        __syncthreads();
        if (tid == 0) nspk_s = 0;
        __syncthreads();

        // ---- phase 3: LIF update, spike list append ----
        for (int n = tid; n < N_TOT; n += 1024) {
            if (n < N_E) {
                float v = v_e[n], i = i_e[n];
                float vd = v + 0.05f * ((0.0f - v) + i);
                bool z = vd > 1.0f;
                v_e[n] = z ? 0.0f : vd;
                i_e[n] = 0.8f * i + I_acc[n];
                if (z) {
                    cnt[n]++;
                    int pos = atomicAdd(&nspk_s, 1);
                    list_s[pos] = n;
                }
            } else {
                int m = n - N_E;
                float v = v_i[m], i = i_i[m];
                float vd = v + 0.1f * ((0.0f - v) + i);
                bool z = vd > 1.0f;
                v_i[m] = z ? 0.0f : vd;
                i_i[m] = 0.8f * i + I_acc[n];
                if (z) {
                    int pos = atomicAdd(&nspk_s, 1);
                    list_s[pos] = n;
                }
            }
        }
        __syncthreads();
    }

    // ---- persist state ----
    for (int n = tid; n < N_E; n += 1024) {
        gv_e[(size_t)b * N_E + n] = v_e[n];
        gi_e[(size_t)b * N_E + n] = i_e[n];
        g_cnt[(size_t)b * N_E + n] = cnt[n];
    }
    for (int n = tid; n < N_I; n += 1024) {
        gv_i[(size_t)b * N_I + n] = v_i[n];
        gi_i[(size_t)b * N_I + n] = i_i[n];
    }
    if (tid == 0) g_nspk[b] = nspk_s;
    for (int s = tid; s < nspk_s; s += 1024) g_list[(size_t)b * N_TOT + s] = list_s[s];
}

// ------------------------------------------------------------------
// Readout: out[b, o] = (1/512) * sum_n cnt[b,n] * rw[o,n] + rb[o]
// ------------------------------------------------------------------
__global__ __launch_bounds__(256) void readout_kernel(
    const unsigned* __restrict__ g_cnt,
    const float* __restrict__ rw, const float* __restrict__ rb, float* __restrict__ out)
{
    int b = blockIdx.x, tid = threadIdx.x;
    float a0 = 0.f, a1 = 0.f, a2 = 0.f;
    for (int n = tid; n < N_E; n += 256) {
        float c = (float)g_cnt[(size_t)b * N_E + n];
        a0 = fmaf(c, rw[n], a0);
        a1 = fmaf(c, rw[N_E + n], a1);
        a2 = fmaf(c, rw[2 * N_E + n], a2);
    }
#pragma unroll
    for (int off = 32; off > 0; off >>= 1) {
        a0 += __shfl_down(a0, off);
        a1 += __shfl_down(a1, off);
        a2 += __shfl_down(a2, off);
    }
    __shared__ float part[3][4];
    int wid = tid >> 6, lane = tid & 63;
    if (lane == 0) { part[0][wid] = a0; part[1][wid] = a1; part[2][wid] = a2; }
    __syncthreads();
    if (tid == 0) {
        float s0 = part[0][0] + part[0][1] + part[0][2] + part[0][3];
        float s1 = part[1][0] + part[1][1] + part[1][2] + part[1][3];
        float s2 = part[2][0] + part[2][1] + part[2][2] + part[2][3];
        const float inv = 1.0f / 512.0f;
        out[b * 3 + 0] = fmaf(s0, inv, rb[0]);
        out[b * 3 + 1] = fmaf(s1, inv, rb[1]);
        out[b * 3 + 2] = fmaf(s2, inv, rb[2]);
    }
}

// ------------------------------------------------------------------
extern "C" void kernel_launch(void* const* d_in, const int* in_sizes, int n_in,
                              void* d_out, int out_size, void* d_ws, size_t ws_size,
                              hipStream_t stream)
{
    const float* x     = (const float*)d_in[0];
    const float* Wee   = (const float*)d_in[1];
    const float* Wie   = (const float*)d_in[2];
    const float* Wei   = (const float*)d_in[3];
    const float* Wii   = (const float*)d_in[4];
    const float* We_in = (const float*)d_in[5];
    const float* Wi_in = (const float*)d_in[6];
    const float* rw    = (const float*)d_in[7];
    const float* rb    = (const float*)d_in[8];
    float* out = (float*)d_out;
    char* ws = (char*)d_ws;

    size_t off = 0;
    auto alloc = [&](size_t bytes) {
        size_t o = off;
        off = (off + bytes + 255) & ~(size_t)255;
        return o;
    };
    size_t o_cnt    = alloc((size_t)N_TOT * 4);
    size_t o_colptr = alloc((size_t)(N_TOT + 1) * 4);
    size_t o_cursor = alloc((size_t)N_TOT * 4);
    size_t o_nzp    = alloc((size_t)CAP * 4);
    size_t o_nzv    = alloc((size_t)CAP * 4);
    size_t o_ve     = alloc((size_t)BATCH * N_E * 4);
    size_t o_ie     = alloc((size_t)BATCH * N_E * 4);
    size_t o_vi     = alloc((size_t)BATCH * N_I * 4);
    size_t o_ii     = alloc((size_t)BATCH * N_I * 4);
    size_t o_gcnt   = alloc((size_t)BATCH * N_E * 4);
    size_t o_glist  = alloc((size_t)BATCH * N_TOT * 4);
    size_t o_gnspk  = alloc((size_t)BATCH * 4);
    size_t o_iinp   = off;   // remainder for the input-projection chunk

    // choose time-chunk size that fits workspace
    int tc = 0;
    if (ws_size > o_iinp) {
        size_t avail = ws_size - o_iinp;
        tc = TSTEPS;
        while (tc >= 2 && (size_t)tc * BATCH * N_TOT * 4 > avail) tc >>= 1;
        if (tc < 2) tc = 0;
    }

    unsigned* p_cnt    = (unsigned*)(ws + o_cnt);
    unsigned* p_colptr = (unsigned*)(ws + o_colptr);
    unsigned* p_cursor = (unsigned*)(ws + o_cursor);
    unsigned* p_nzp    = (unsigned*)(ws + o_nzp);
    float*    p_nzv    = (float*)(ws + o_nzv);
    float*    p_ve     = (float*)(ws + o_ve);
    float*    p_ie     = (float*)(ws + o_ie);
    float*    p_vi     = (float*)(ws + o_vi);
    float*    p_ii     = (float*)(ws + o_ii);
    unsigned* p_gcnt   = (unsigned*)(ws + o_gcnt);
    int*      p_glist  = (int*)(ws + o_glist);
    int*      p_gnspk  = (int*)(ws + o_gnspk);
    float*    p_iinp   = (float*)(ws + o_iinp);

    // ---- build CSC of relu'd sparse weights (per launch; inputs may differ) ----
    hipMemsetAsync(ws + o_cnt, 0, (size_t)N_TOT * 4, stream);
    const long total = (long)N_E * N_E + (long)N_I * N_E + (long)N_E * N_I + (long)N_I * N_I;
    int nblk = (int)((total + 255) / 256);
    count_kernel<<<nblk, 256, 0, stream>>>(Wee, Wie, Wei, Wii, p_cnt);
    scan_kernel<<<1, 256, 0, stream>>>(p_cnt, p_colptr, p_cursor);
    fill_kernel<<<nblk, 256, 0, stream>>>(Wee, Wie, Wei, Wii, p_cursor, p_nzp, p_nzv);

    // ---- time loop: proj GEMM chunk + persistent sim ----
    if (tc >= 2) {
        for (int t0 = 0; t0 < TSTEPS; t0 += tc) {
            dim3 pg(N_TOT / PBN, (tc * BATCH) / PBM);
            proj_kernel<<<pg, 256, 0, stream>>>(x, We_in, Wi_in, p_iinp, t0);
            sim_kernel<<<BATCH, 1024, 0, stream>>>(
                p_iinp, x, We_in, Wi_in, p_colptr, p_nzp, p_nzv,
                p_ve, p_ie, p_vi, p_ii, p_gcnt, p_glist, p_gnspk,
                t0, tc, (t0 == 0) ? 1 : 0);
        }
    } else {
        // workspace too small for precompute: compute projection on the fly
        sim_kernel<<<BATCH, 1024, 0, stream>>>(
            nullptr, x, We_in, Wi_in, p_colptr, p_nzp, p_nzv,
            p_ve, p_ie, p_vi, p_ii, p_gcnt, p_glist, p_gnspk,
            0, TSTEPS, 1);
    }

    // ---- readout ----
    readout_kernel<<<BATCH, 256, 0, stream>>>(p_gcnt, rw, rb, out);
}

// Round 2
// 3419.483 us; speedup vs baseline: 1.1940x; 1.1940x over previous
//
#include <hip/hip_runtime.h>
#include <cstdint>
#include <cstddef>

#define N_E 2048
#define N_I 512
#define N_TOT 2560
#define BATCH 64
#define TSTEPS 512
#define INDIM 128
#define CAP (1u << 20)   // nz capacity (expected ~330K)

// ------------------------------------------------------------------
// CSC build: counts -> scan -> fill.
//   col 0..2047   : E presynaptic j  (Wee -> post 0..2047 (+), Wie -> 2048+r (+))
//   col 2048..2559: I presynaptic j  (Wei -> post 0..2047 (-), Wii -> 2048+r (-))
// ------------------------------------------------------------------
__global__ void count_kernel(const float* __restrict__ Wee, const float* __restrict__ Wie,
                             const float* __restrict__ Wei, const float* __restrict__ Wii,
                             unsigned* __restrict__ cnt)
{
    const long EE = (long)N_E * N_E;
    const long IE = (long)N_I * N_E;
    const long EI = (long)N_E * N_I;
    const long II = (long)N_I * N_I;
    long idx = (long)blockIdx.x * 256 + threadIdx.x;
    long total = EE + IE + EI + II;
    if (idx >= total) return;
    float v; int col;
    if (idx < EE) {
        v = Wee[idx]; col = (int)(idx & (N_E - 1));
    } else if (idx < EE + IE) {
        long j = idx - EE; v = Wie[j]; col = (int)(j & (N_E - 1));
    } else if (idx < EE + IE + EI) {
        long j = idx - EE - IE; v = Wei[j]; col = N_E + (int)(j & (N_I - 1));
    } else {
        long j = idx - EE - IE - EI; v = Wii[j]; col = N_E + (int)(j & (N_I - 1));
    }
    if (v > 0.0f) atomicAdd(&cnt[col], 1u);
}

__global__ void scan_kernel(const unsigned* __restrict__ cnt,
                            unsigned* __restrict__ colptr, unsigned* __restrict__ cursor)
{
    __shared__ unsigned sums[256];
    int t = threadIdx.x;
    int base = t * 10;                 // 2560 = 256 * 10
    unsigned loc[10];
    unsigned s = 0;
    for (int i = 0; i < 10; ++i) { loc[i] = s; s += cnt[base + i]; }
    sums[t] = s;
    __syncthreads();
    if (t == 0) {
        unsigned a = 0;
        for (int i = 0; i < 256; ++i) { unsigned v = sums[i]; sums[i] = a; a += v; }
    }
    __syncthreads();
    unsigned offt = sums[t];
    for (int i = 0; i < 10; ++i) {
        unsigned v = offt + loc[i];
        if (v > CAP) v = CAP;
        colptr[base + i] = v;
        cursor[base + i] = v;
    }
    if (t == 255) {
        unsigned tot = offt + s;
        if (tot > CAP) tot = CAP;
        colptr[N_TOT] = tot;
    }
}

__global__ void fill_kernel(const float* __restrict__ Wee, const float* __restrict__ Wie,
                            const float* __restrict__ Wei, const float* __restrict__ Wii,
                            unsigned* __restrict__ cursor,
                            unsigned short* __restrict__ nzp, float* __restrict__ nzv)
{
    const long EE = (long)N_E * N_E;
    const long IE = (long)N_I * N_E;
    const long EI = (long)N_E * N_I;
    const long II = (long)N_I * N_I;
    long idx = (long)blockIdx.x * 256 + threadIdx.x;
    long total = EE + IE + EI + II;
    if (idx >= total) return;
    float v; int col; int post; bool neg;
    if (idx < EE) {
        int r = (int)(idx >> 11), c = (int)(idx & (N_E - 1));
        v = Wee[idx]; post = r; col = c; neg = false;
    } else if (idx < EE + IE) {
        long j = idx - EE;
        int r = (int)(j >> 11), c = (int)(j & (N_E - 1));
        v = Wie[j]; post = N_E + r; col = c; neg = false;
    } else if (idx < EE + IE + EI) {
        long j = idx - EE - IE;
        int r = (int)(j >> 9), c = (int)(j & (N_I - 1));
        v = Wei[j]; post = r; col = N_E + c; neg = true;
    } else {
        long j = idx - EE - IE - EI;
        int r = (int)(j >> 9), c = (int)(j & (N_I - 1));
        v = Wii[j]; post = N_E + r; col = N_E + c; neg = true;
    }
    if (v > 0.0f) {
        unsigned pos = atomicAdd(&cursor[col], 1u);
        if (pos < CAP) {
            nzp[pos] = (unsigned short)post;
            nzv[pos] = neg ? -v : v;
        }
    }
}

// ------------------------------------------------------------------
// Input projection GEMM: out[(tl*64+b)*2560 + n] = dot(x[b, t0+tl, :], W[n, :])
// ------------------------------------------------------------------
#define PBM 128
#define PBN 64
#define PBK 32
__global__ __launch_bounds__(256) void proj_kernel(
    const float* __restrict__ x, const float* __restrict__ We, const float* __restrict__ Wi,
    float* __restrict__ out, int t0)
{
    __shared__ __align__(16) float As[PBK][132];
    __shared__ __align__(16) float Bs[PBK][68];
    int tid = threadIdx.x;
    int bx = blockIdx.x, by = blockIdx.y;
    int tx = tid & 15, ty = tid >> 4;
    float acc[8][4];
#pragma unroll
    for (int i = 0; i < 8; ++i)
#pragma unroll
        for (int j = 0; j < 4; ++j) acc[i][j] = 0.0f;

    for (int kb = 0; kb < INDIM; kb += PBK) {
#pragma unroll
        for (int it = 0; it < 4; ++it) {
            int idx = it * 256 + tid;
            int kq = idx & 7, ml = idx >> 3;
            int m = by * PBM + ml;
            int b = m & 63, tl = m >> 6;
            const float* arow = x + ((size_t)b * TSTEPS + (size_t)(t0 + tl)) * INDIM;
            float4 v = *(const float4*)(arow + kb + kq * 4);
            As[kq * 4 + 0][ml] = v.x; As[kq * 4 + 1][ml] = v.y;
            As[kq * 4 + 2][ml] = v.z; As[kq * 4 + 3][ml] = v.w;
        }
#pragma unroll
        for (int it = 0; it < 2; ++it) {
            int idx = it * 256 + tid;
            int kq = idx & 7, nl = idx >> 3;
            int n = bx * PBN + nl;
            const float* brow = (n < N_E) ? (We + (size_t)n * INDIM)
                                          : (Wi + (size_t)(n - N_E) * INDIM);
            float4 v = *(const float4*)(brow + kb + kq * 4);
            Bs[kq * 4 + 0][nl] = v.x; Bs[kq * 4 + 1][nl] = v.y;
            Bs[kq * 4 + 2][nl] = v.z; Bs[kq * 4 + 3][nl] = v.w;
        }
        __syncthreads();
#pragma unroll
        for (int k = 0; k < PBK; ++k) {
            float4 a0 = *(const float4*)&As[k][ty * 8];
            float4 a1 = *(const float4*)&As[k][ty * 8 + 4];
            float4 b0 = *(const float4*)&Bs[k][tx * 4];
            float a[8] = {a0.x, a0.y, a0.z, a0.w, a1.x, a1.y, a1.z, a1.w};
            float bb[4] = {b0.x, b0.y, b0.z, b0.w};
#pragma unroll
            for (int i = 0; i < 8; ++i)
#pragma unroll
                for (int j = 0; j < 4; ++j)
                    acc[i][j] = fmaf(a[i], bb[j], acc[i][j]);
        }
        __syncthreads();
    }
#pragma unroll
    for (int i = 0; i < 8; ++i) {
        int m = by * PBM + ty * 8 + i;
        float4 o = make_float4(acc[i][0], acc[i][1], acc[i][2], acc[i][3]);
        *(float4*)(out + (size_t)m * N_TOT + bx * PBN + tx * 4) = o;
    }
}

// ------------------------------------------------------------------
// on-the-fly input projection for one neuron (fallback path only)
// ------------------------------------------------------------------
__device__ __forceinline__ float inline_proj(const float* __restrict__ x,
                                             const float* __restrict__ We_in,
                                             const float* __restrict__ Wi_in,
                                             int b, int t, int n)
{
    const float* xr = x + ((size_t)b * TSTEPS + (size_t)t) * INDIM;
    const float* wr = (n < N_E) ? (We_in + (size_t)n * INDIM)
                                : (Wi_in + (size_t)(n - N_E) * INDIM);
    float a = 0.f;
#pragma unroll
    for (int k = 0; k < INDIM; k += 4) {
        float4 w = *(const float4*)(wr + k);
        float4 xv = *(const float4*)(xr + k);
        a = fmaf(w.x, xv.x, a);
        a = fmaf(w.y, xv.y, a);
        a = fmaf(w.z, xv.z, a);
        a = fmaf(w.w, xv.w, a);
    }
    return a;
}

// ------------------------------------------------------------------
// Persistent per-batch LIF sim over tc steps. One block per batch.
// Double-buffered I_acc / spike lists; 2 barriers per step;
// wave-aggregated spike-list append; prefetched input rows.
// ------------------------------------------------------------------
__global__ __launch_bounds__(1024) void sim_kernel(
    const float* __restrict__ i_inp,   // precomputed input currents; may be null
    const float* __restrict__ x, const float* __restrict__ We_in, const float* __restrict__ Wi_in,
    const unsigned* __restrict__ colptr, const unsigned short* __restrict__ nzp,
    const float* __restrict__ nzv,
    float* __restrict__ gv_e, float* __restrict__ gi_e,
    float* __restrict__ gv_i, float* __restrict__ gi_i,
    unsigned* __restrict__ g_cnt, int* __restrict__ g_list, int* __restrict__ g_nspk,
    int t0, int tc, int first)
{
    __shared__ float v_e[N_E], i_e[N_E];
    __shared__ float v_i[N_I], i_i[N_I];
    __shared__ float I_acc[2][N_TOT];
    __shared__ unsigned cnt[N_E];
    __shared__ int list_s[2][N_TOT];
    __shared__ int nspk_s[2];

    int b = blockIdx.x, tid = threadIdx.x;
    int lane = tid & 63, wid = tid >> 6;

    if (first) {
        for (int n = tid; n < N_E; n += 1024) { v_e[n] = 0.f; i_e[n] = 0.f; cnt[n] = 0u; }
        for (int n = tid; n < N_I; n += 1024) { v_i[n] = 0.f; i_i[n] = 0.f; }
        if (tid == 0) nspk_s[0] = 0;
    } else {
        for (int n = tid; n < N_E; n += 1024) {
            v_e[n] = gv_e[(size_t)b * N_E + n];
            i_e[n] = gi_e[(size_t)b * N_E + n];
            cnt[n] = g_cnt[(size_t)b * N_E + n];
        }
        for (int n = tid; n < N_I; n += 1024) {
            v_i[n] = gv_i[(size_t)b * N_I + n];
            i_i[n] = gi_i[(size_t)b * N_I + n];
        }
        if (tid == 0) nspk_s[0] = g_nspk[b];
        __syncthreads();
        for (int s = tid; s < nspk_s[0]; s += 1024) list_s[0][s] = g_list[(size_t)b * N_TOT + s];
    }
    // init I_acc[0] with input row for first step of this chunk
    if (i_inp) {
        const float* src = i_inp + (size_t)b * N_TOT;    // tl = 0
        for (int n = tid; n < N_TOT; n += 1024) I_acc[0][n] = src[n];
    } else {
        for (int n = tid; n < N_TOT; n += 1024)
            I_acc[0][n] = inline_proj(x, We_in, Wi_in, b, t0, n);
    }
    __syncthreads();

    for (int tl = 0; tl < tc; ++tl) {
        int cur = tl & 1, nxt = cur ^ 1;

        // ---- phase A: prefetch next input row; scatter this step's incoming spikes ----
        float pf0 = 0.f, pf1 = 0.f, pf2 = 0.f;
        bool havepf = (i_inp != nullptr) && (tl + 1 < tc);
        if (havepf) {
            const float* src = i_inp + ((size_t)(tl + 1) * BATCH + b) * N_TOT;
            pf0 = src[tid];
            pf1 = src[tid + 1024];
            if (tid < N_TOT - 2048) pf2 = src[tid + 2048];
        }
        if (tid == 0) nspk_s[nxt] = 0;

        int ns = nspk_s[cur];
        for (int s = wid; s < ns; s += 16) {
            int j = list_s[cur][s];
            unsigned beg = colptr[j], end = colptr[j + 1];
            for (unsigned p = beg + lane; p < end; p += 64)
                atomicAdd(&I_acc[cur][nzp[p]], nzv[p]);
        }
        __syncthreads();

        // ---- phase B: LIF update + aggregated spike append + next-input commit ----
#pragma unroll
        for (int it = 0; it < 3; ++it) {
            int n = tid + it * 1024;
            if (n >= N_TOT) break;              // whole waves drop out together
            float I = I_acc[cur][n];
            bool z;
            if (n < N_E) {
                float v = v_e[n], i = i_e[n];
                float vd = v + 0.05f * ((0.0f - v) + i);
                z = vd > 1.0f;
                v_e[n] = z ? 0.0f : vd;
                i_e[n] = 0.8f * i + I;
                if (z) cnt[n]++;
            } else {
                int m = n - N_E;
                float v = v_i[m], i = i_i[m];
                float vd = v + 0.1f * ((0.0f - v) + i);
                z = vd > 1.0f;
                v_i[m] = z ? 0.0f : vd;
                i_i[m] = 0.8f * i + I;
            }
            unsigned long long msk = __ballot(z);
            int wc = __popcll(msk);
            if (wc) {
                int base = 0;
                if (lane == 0) base = atomicAdd(&nspk_s[nxt], wc);
                base = __shfl(base, 0);
                if (z) list_s[nxt][base + __popcll(msk & ((1ull << lane) - 1ull))] = n;
            }
            if (tl + 1 < tc) {
                if (i_inp) {
                    I_acc[nxt][n] = (it == 0) ? pf0 : (it == 1) ? pf1 : pf2;
                } else {
                    I_acc[nxt][n] = inline_proj(x, We_in, Wi_in, b, t0 + tl + 1, n);
                }
            }
        }
        __syncthreads();
    }

    // ---- persist state (tc is even -> pending spike list is buffer 0) ----
    for (int n = tid; n < N_E; n += 1024) {
        gv_e[(size_t)b * N_E + n] = v_e[n];
        gi_e[(size_t)b * N_E + n] = i_e[n];
        g_cnt[(size_t)b * N_E + n] = cnt[n];
    }
    for (int n = tid; n < N_I; n += 1024) {
        gv_i[(size_t)b * N_I + n] = v_i[n];
        gi_i[(size_t)b * N_I + n] = i_i[n];
    }
    if (tid == 0) g_nspk[b] = nspk_s[0];
    for (int s = tid; s < nspk_s[0]; s += 1024) g_list[(size_t)b * N_TOT + s] = list_s[0][s];
}

// ------------------------------------------------------------------
// Readout: out[b, o] = (1/512) * sum_n cnt[b,n] * rw[o,n] + rb[o]
// ------------------------------------------------------------------
__global__ __launch_bounds__(256) void readout_kernel(
    const unsigned* __restrict__ g_cnt,
    const float* __restrict__ rw, const float* __restrict__ rb, float* __restrict__ out)
{
    int b = blockIdx.x, tid = threadIdx.x;
    float a0 = 0.f, a1 = 0.f, a2 = 0.f;
    for (int n = tid; n < N_E; n += 256) {
        float c = (float)g_cnt[(size_t)b * N_E + n];
        a0 = fmaf(c, rw[n], a0);
        a1 = fmaf(c, rw[N_E + n], a1);
        a2 = fmaf(c, rw[2 * N_E + n], a2);
    }
#pragma unroll
    for (int off = 32; off > 0; off >>= 1) {
        a0 += __shfl_down(a0, off);
        a1 += __shfl_down(a1, off);
        a2 += __shfl_down(a2, off);
    }
    __shared__ float part[3][4];
    int wid = tid >> 6, lane = tid & 63;
    if (lane == 0) { part[0][wid] = a0; part[1][wid] = a1; part[2][wid] = a2; }
    __syncthreads();
    if (tid == 0) {
        float s0 = part[0][0] + part[0][1] + part[0][2] + part[0][3];
        float s1 = part[1][0] + part[1][1] + part[1][2] + part[1][3];
        float s2 = part[2][0] + part[2][1] + part[2][2] + part[2][3];
        const float inv = 1.0f / 512.0f;
        out[b * 3 + 0] = fmaf(s0, inv, rb[0]);
        out[b * 3 + 1] = fmaf(s1, inv, rb[1]);
        out[b * 3 + 2] = fmaf(s2, inv, rb[2]);
    }
}

// ------------------------------------------------------------------
extern "C" void kernel_launch(void* const* d_in, const int* in_sizes, int n_in,
                              void* d_out, int out_size, void* d_ws, size_t ws_size,
                              hipStream_t stream)
{
    const float* x     = (const float*)d_in[0];
    const float* Wee   = (const float*)d_in[1];
    const float* Wie   = (const float*)d_in[2];
    const float* Wei   = (const float*)d_in[3];
    const float* Wii   = (const float*)d_in[4];
    const float* We_in = (const float*)d_in[5];
    const float* Wi_in = (const float*)d_in[6];
    const float* rw    = (const float*)d_in[7];
    const float* rb    = (const float*)d_in[8];
    float* out = (float*)d_out;
    char* ws = (char*)d_ws;

    size_t off = 0;
    auto alloc = [&](size_t bytes) {
        size_t o = off;
        off = (off + bytes + 255) & ~(size_t)255;
        return o;
    };
    size_t o_cnt    = alloc((size_t)N_TOT * 4);
    size_t o_colptr = alloc((size_t)(N_TOT + 1) * 4);
    size_t o_cursor = alloc((size_t)N_TOT * 4);
    size_t o_nzp    = alloc((size_t)CAP * 2);   // u16 post indices
    size_t o_nzv    = alloc((size_t)CAP * 4);
    size_t o_ve     = alloc((size_t)BATCH * N_E * 4);
    size_t o_ie     = alloc((size_t)BATCH * N_E * 4);
    size_t o_vi     = alloc((size_t)BATCH * N_I * 4);
    size_t o_ii     = alloc((size_t)BATCH * N_I * 4);
    size_t o_gcnt   = alloc((size_t)BATCH * N_E * 4);
    size_t o_glist  = alloc((size_t)BATCH * N_TOT * 4);
    size_t o_gnspk  = alloc((size_t)BATCH * 4);
    size_t o_iinp   = off;   // remainder for the input-projection chunk

    int tc = 0;
    if (ws_size > o_iinp) {
        size_t avail = ws_size - o_iinp;
        tc = TSTEPS;
        while (tc >= 2 && (size_t)tc * BATCH * N_TOT * 4 > avail) tc >>= 1;
        if (tc < 2) tc = 0;
    }

    unsigned*       p_cnt    = (unsigned*)(ws + o_cnt);
    unsigned*       p_colptr = (unsigned*)(ws + o_colptr);
    unsigned*       p_cursor = (unsigned*)(ws + o_cursor);
    unsigned short* p_nzp    = (unsigned short*)(ws + o_nzp);
    float*          p_nzv    = (float*)(ws + o_nzv);
    float*          p_ve     = (float*)(ws + o_ve);
    float*          p_ie     = (float*)(ws + o_ie);
    float*          p_vi     = (float*)(ws + o_vi);
    float*          p_ii     = (float*)(ws + o_ii);
    unsigned*       p_gcnt   = (unsigned*)(ws + o_gcnt);
    int*            p_glist  = (int*)(ws + o_glist);
    int*            p_gnspk  = (int*)(ws + o_gnspk);
    float*          p_iinp   = (float*)(ws + o_iinp);

    // ---- build CSC of relu'd sparse weights ----
    hipMemsetAsync(ws + o_cnt, 0, (size_t)N_TOT * 4, stream);
    const long total = (long)N_E * N_E + (long)N_I * N_E + (long)N_E * N_I + (long)N_I * N_I;
    int nblk = (int)((total + 255) / 256);
    count_kernel<<<nblk, 256, 0, stream>>>(Wee, Wie, Wei, Wii, p_cnt);
    scan_kernel<<<1, 256, 0, stream>>>(p_cnt, p_colptr, p_cursor);
    fill_kernel<<<nblk, 256, 0, stream>>>(Wee, Wie, Wei, Wii, p_cursor, p_nzp, p_nzv);

    // ---- time loop: proj GEMM chunk + persistent sim ----
    if (tc >= 2) {
        for (int t0 = 0; t0 < TSTEPS; t0 += tc) {
            dim3 pg(N_TOT / PBN, (tc * BATCH) / PBM);
            proj_kernel<<<pg, 256, 0, stream>>>(x, We_in, Wi_in, p_iinp, t0);
            sim_kernel<<<BATCH, 1024, 0, stream>>>(
                p_iinp, x, We_in, Wi_in, p_colptr, p_nzp, p_nzv,
                p_ve, p_ie, p_vi, p_ii, p_gcnt, p_glist, p_gnspk,
                t0, tc, (t0 == 0) ? 1 : 0);
        }
    } else {
        sim_kernel<<<BATCH, 1024, 0, stream>>>(
            nullptr, x, We_in, Wi_in, p_colptr, p_nzp, p_nzv,
            p_ve, p_ie, p_vi, p_ii, p_gcnt, p_glist, p_gnspk,
            0, TSTEPS, 1);
    }

    // ---- readout ----
    readout_kernel<<<BATCH, 256, 0, stream>>>(p_gcnt, rw, rb, out);
}